// Round 1
// baseline (304.234 us; speedup 1.0000x reference)
//
#include <hip/hip_runtime.h>
#include <hip/hip_bf16.h>
#include <cstddef>

#define D_DIM 768
#define V_DIM 10240
#define ROWS 32768   // B*N = 8*4096
#define BM 128
#define BN 128
#define BK 32

using bf16x8 = __attribute__((ext_vector_type(8))) __bf16;
using f32x4  = __attribute__((ext_vector_type(4))) float;

// ---------------------------------------------------------------------------
// Pre-pass: fold permutation + 2*(x-0.5) affine into weights.
// W'[d][j] = 2 * W[d][perm(j)],  perm(j) = (j%3)*256 + (j/48)*16 + (j/3)%16
// bias[d]  = -sum_k W[d][k]
// ---------------------------------------------------------------------------
__global__ void prep_w(const float* __restrict__ W, __bf16* __restrict__ Wp,
                       float* __restrict__ bias) {
    int d = blockIdx.x;
    int t = threadIdx.x;
    float s = 0.f;
    for (int j = t; j < D_DIM; j += 256) {
        int c  = j % 3;
        int pw = (j / 3) & 15;
        int ph = j / 48;
        int k  = c * 256 + ph * 16 + pw;
        float w = W[d * D_DIM + k];
        Wp[d * D_DIM + j] = (__bf16)(2.0f * w);
        s += w;
    }
    __shared__ float red[256];
    red[t] = s;
    __syncthreads();
    for (int off = 128; off > 0; off >>= 1) {
        if (t < off) red[t] += red[t + off];
        __syncthreads();
    }
    if (t == 0) bias[d] = -red[0];
}

// ---------------------------------------------------------------------------
// Aux outputs: position_ids = coord reversed (as fp32), padding = !valid
// ---------------------------------------------------------------------------
__global__ void aux_out(const int* __restrict__ coord, const int* __restrict__ valid,
                        float* __restrict__ out1, float* __restrict__ out2) {
    int i = blockIdx.x * blockDim.x + threadIdx.x;
    if (i < ROWS) {
        int c0 = coord[2 * i];
        int c1 = coord[2 * i + 1];
        out1[2 * i]     = (float)c1;
        out1[2 * i + 1] = (float)c0;
        out2[i] = valid[i] ? 0.0f : 1.0f;
    }
}

// ---------------------------------------------------------------------------
// Main GEMM: out[m][d] = sum_k x[m][k]*Wp[d][k] + bias[d] + pos[m][d]
// 128x128 tile, BK=32, 4 waves (2x2 of 64x64), 16x16x32 bf16 MFMA, 4x4 acc.
// ---------------------------------------------------------------------------
__launch_bounds__(256)
__global__ void gemm_pos(const float* __restrict__ X, const __bf16* __restrict__ Wp,
                         const float* __restrict__ bias, const float* __restrict__ ptab,
                         const int* __restrict__ coord, const int* __restrict__ valid,
                         float* __restrict__ out) {
    __shared__ __align__(16) __bf16 la[BM * BK];
    __shared__ __align__(16) __bf16 lb[BN * BK];

    const int n0 = blockIdx.x * BN;   // 6 n-tiles (fast axis)
    const int m0 = blockIdx.y * BM;   // 256 m-tiles

    const int tid  = threadIdx.x;
    const int lane = tid & 63;
    const int wave = tid >> 6;
    const int wr   = (wave >> 1) * 64;   // wave row offset in tile
    const int wc   = (wave & 1) * 64;    // wave col offset in tile
    const int lr   = lane & 15;
    const int kq   = (lane >> 4) * 8;    // k-quad offset for A/B fragments

    f32x4 acc[4][4] = {};

    for (int kt = 0; kt < D_DIM / BK; ++kt) {
        const int k0 = kt * BK;

        // --- B staging: global_load_lds width=16, bf16 weights ---
        #pragma unroll
        for (int i = 0; i < 2; ++i) {
            int idx = i * 2048 + tid * 8;        // bf16 element index in tile
            int row = idx >> 5;                  // /32
            int col = idx & 31;
            const __bf16* src = Wp + (size_t)(n0 + row) * D_DIM + k0 + col;
            __builtin_amdgcn_global_load_lds(
                (const __attribute__((address_space(1))) void*)src,
                (__attribute__((address_space(3))) void*)&lb[idx], 16, 0, 0);
        }

        // --- A staging: fp32 x -> bf16 LDS (fused convert) ---
        #pragma unroll
        for (int i = 0; i < 2; ++i) {
            int idx = i * 2048 + tid * 8;
            int row = idx >> 5;
            int col = idx & 31;
            const float4* src = (const float4*)(X + (size_t)(m0 + row) * D_DIM + k0 + col);
            float4 f0 = src[0];
            float4 f1 = src[1];
            bf16x8 v;
            v[0] = (__bf16)f0.x; v[1] = (__bf16)f0.y; v[2] = (__bf16)f0.z; v[3] = (__bf16)f0.w;
            v[4] = (__bf16)f1.x; v[5] = (__bf16)f1.y; v[6] = (__bf16)f1.z; v[7] = (__bf16)f1.w;
            *(bf16x8*)&la[idx] = v;
        }

        __syncthreads();

        bf16x8 af[4], bfr[4];
        #pragma unroll
        for (int i = 0; i < 4; ++i)
            af[i] = *(const bf16x8*)&la[(wr + i * 16 + lr) * BK + kq];
        #pragma unroll
        for (int j = 0; j < 4; ++j)
            bfr[j] = *(const bf16x8*)&lb[(wc + j * 16 + lr) * BK + kq];

        #pragma unroll
        for (int i = 0; i < 4; ++i)
            #pragma unroll
            for (int j = 0; j < 4; ++j)
                acc[i][j] = __builtin_amdgcn_mfma_f32_16x16x32_bf16(af[i], bfr[j], acc[i][j], 0, 0, 0);

        __syncthreads();
    }

    // --- Epilogue: bias + positional gather + store ---
    const float* pt0 = ptab;
    const float* pt1 = ptab + (size_t)V_DIM * D_DIM;
    const int rq = (lane >> 4) * 4;      // C/D row quad

    float bvals[4];
    #pragma unroll
    for (int j = 0; j < 4; ++j)
        bvals[j] = bias[n0 + wc + j * 16 + lr];

    #pragma unroll
    for (int i = 0; i < 4; ++i) {
        #pragma unroll
        for (int r = 0; r < 4; ++r) {
            int m = m0 + wr + i * 16 + rq + r;
            int c0 = coord[2 * m];
            int c1 = coord[2 * m + 1];
            if (c0 < 0) c0 = 0;
            if (c1 < 0) c1 = 0;
            int vld = valid[m];
            #pragma unroll
            for (int j = 0; j < 4; ++j) {
                int d = n0 + wc + j * 16 + lr;
                float v = acc[i][j][r] + bvals[j];
                if (vld)
                    v += pt0[(size_t)c1 * D_DIM + d] + pt1[(size_t)c0 * D_DIM + d];
                out[(size_t)m * D_DIM + d] = v;
            }
        }
    }
}

extern "C" void kernel_launch(void* const* d_in, const int* in_sizes, int n_in,
                              void* d_out, int out_size, void* d_ws, size_t ws_size,
                              hipStream_t stream) {
    const float* x     = (const float*)d_in[0];
    const int*   coord = (const int*)d_in[1];
    const int*   valid = (const int*)d_in[2];
    const float* W     = (const float*)d_in[3];
    const float* ptab  = (const float*)d_in[4];

    float* out0 = (float*)d_out;                       // [32768][768]
    float* out1 = out0 + (size_t)ROWS * D_DIM;         // [32768][2]
    float* out2 = out1 + (size_t)ROWS * 2;             // [32768]

    __bf16* Wp  = (__bf16*)d_ws;                               // 768*768 bf16
    float*  bias = (float*)((char*)d_ws + (size_t)D_DIM * D_DIM * sizeof(__bf16));

    hipLaunchKernelGGL(prep_w, dim3(D_DIM), dim3(256), 0, stream, W, Wp, bias);
    hipLaunchKernelGGL(aux_out, dim3(ROWS / 256), dim3(256), 0, stream, coord, valid, out1, out2);
    hipLaunchKernelGGL(gemm_pos, dim3(D_DIM / BN, ROWS / BM), dim3(256), 0, stream,
                       x, Wp, bias, ptab, coord, valid, out0);
}

// Round 2
// 303.077 us; speedup vs baseline: 1.0038x; 1.0038x over previous
//
#include <hip/hip_runtime.h>
#include <hip/hip_bf16.h>
#include <cstddef>

#define D_DIM 768
#define V_DIM 10240
#define ROWS 32768   // B*N = 8*4096
#define BM 128
#define BN 128
#define BK 32
#define SA 40        // padded A row stride in bf16 elems (80 B -> conflict-free reads)

using bf16x8 = __attribute__((ext_vector_type(8))) __bf16;
using f32x4  = __attribute__((ext_vector_type(4))) float;

// ---------------------------------------------------------------------------
// Pre-pass: fold permutation + 2*(x-0.5) affine into weights.
// W'[d][j] = 2 * W[d][perm(j)],  perm(j) = (j%3)*256 + (j/48)*16 + (j/3)%16
// bias[d]  = -sum_k W[d][k]
// ---------------------------------------------------------------------------
__global__ void prep_w(const float* __restrict__ W, __bf16* __restrict__ Wp,
                       float* __restrict__ bias) {
    int d = blockIdx.x;
    int t = threadIdx.x;
    float s = 0.f;
    for (int j = t; j < D_DIM; j += 256) {
        int c  = j % 3;
        int pw = (j / 3) & 15;
        int ph = j / 48;
        int k  = c * 256 + ph * 16 + pw;
        float w = W[d * D_DIM + k];
        Wp[d * D_DIM + j] = (__bf16)(2.0f * w);
        s += w;
    }
    __shared__ float red[256];
    red[t] = s;
    __syncthreads();
    for (int off = 128; off > 0; off >>= 1) {
        if (t < off) red[t] += red[t + off];
        __syncthreads();
    }
    if (t == 0) bias[d] = -red[0];
}

// ---------------------------------------------------------------------------
// Aux outputs: position_ids = coord reversed (as fp32), padding = !valid
// ---------------------------------------------------------------------------
__global__ void aux_out(const int* __restrict__ coord, const int* __restrict__ valid,
                        float* __restrict__ out1, float* __restrict__ out2) {
    int i = blockIdx.x * blockDim.x + threadIdx.x;
    if (i < ROWS) {
        int c0 = coord[2 * i];
        int c1 = coord[2 * i + 1];
        out1[2 * i]     = (float)c1;
        out1[2 * i + 1] = (float)c0;
        out2[i] = valid[i] ? 0.0f : 1.0f;
    }
}

// ---------------------------------------------------------------------------
// Main GEMM: out[m][d] = sum_k x[m][k]*Wp[d][k] + bias[d] + pos[m][d]
// 128x128 tile, BK=32, 4 waves (2x2 of 64x64), 16x16x32 bf16 MFMA, 4x4 acc.
// LDS conflict scheme:
//   A: padded stride 40 elems -> read quad (5r+g)%8, 2-way (free).
//   B: global_load_lds (contiguous), source chunk XOR-swizzled by ((row>>1)&3)
//      -> read quad (4r + g^s(r))%8 covers all 8 quads exactly 2x (free).
// ---------------------------------------------------------------------------
__launch_bounds__(256)
__global__ void gemm_pos(const float* __restrict__ X, const __bf16* __restrict__ Wp,
                         const float* __restrict__ bias, const float* __restrict__ ptab,
                         const int* __restrict__ coord, const int* __restrict__ valid,
                         float* __restrict__ out) {
    __shared__ __align__(16) __bf16 la[BM * SA];   // 10240 B
    __shared__ __align__(16) __bf16 lb[BN * BK];   // 8192 B

    const int n0 = blockIdx.x * BN;   // 6 n-tiles (fast axis)
    const int m0 = blockIdx.y * BM;   // 256 m-tiles

    const int tid  = threadIdx.x;
    const int lane = tid & 63;
    const int wave = tid >> 6;
    const int wr   = (wave >> 1) * 64;   // wave row offset in tile
    const int wc   = (wave & 1) * 64;    // wave col offset in tile
    const int lr   = lane & 15;
    const int g    = lane >> 4;          // k-quad group (0..3)
    const int kq   = g * 8;              // k offset for A fragments
    const int pB   = (g ^ ((lr >> 1) & 3)) * 8;  // swizzled k offset for B reads

    f32x4 acc[4][4] = {};

    for (int kt = 0; kt < D_DIM / BK; ++kt) {
        const int k0 = kt * BK;

        // --- B staging: global_load_lds width=16, XOR chunk swizzle ---
        #pragma unroll
        for (int i = 0; i < 2; ++i) {
            int row   = i * 64 + (tid >> 2);            // LDS row this lane fills
            int chunk = (tid & 3) ^ ((row >> 1) & 3);   // global 16B chunk fetched
            const __bf16* src = Wp + (size_t)(n0 + row) * D_DIM + k0 + chunk * 8;
            int ldsoff = i * 2048 + tid * 8;            // contiguous lane order
            __builtin_amdgcn_global_load_lds(
                (const __attribute__((address_space(1))) void*)src,
                (__attribute__((address_space(3))) void*)&lb[ldsoff], 16, 0, 0);
        }

        // --- A staging: fp32 x -> bf16 LDS (fused convert), padded stride ---
        #pragma unroll
        for (int i = 0; i < 2; ++i) {
            int idx = i * 2048 + tid * 8;   // logical (unpadded) elem index
            int row = idx >> 5;
            int col = idx & 31;
            const float4* src = (const float4*)(X + (size_t)(m0 + row) * D_DIM + k0 + col);
            float4 f0 = src[0];
            float4 f1 = src[1];
            bf16x8 v;
            v[0] = (__bf16)f0.x; v[1] = (__bf16)f0.y; v[2] = (__bf16)f0.z; v[3] = (__bf16)f0.w;
            v[4] = (__bf16)f1.x; v[5] = (__bf16)f1.y; v[6] = (__bf16)f1.z; v[7] = (__bf16)f1.w;
            *(bf16x8*)&la[row * SA + col] = v;
        }

        __syncthreads();

        bf16x8 af[4], bfr[4];
        #pragma unroll
        for (int i = 0; i < 4; ++i)
            af[i] = *(const bf16x8*)&la[(wr + i * 16 + lr) * SA + kq];
        #pragma unroll
        for (int j = 0; j < 4; ++j)
            bfr[j] = *(const bf16x8*)&lb[(wc + j * 16 + lr) * BK + pB];

        #pragma unroll
        for (int i = 0; i < 4; ++i)
            #pragma unroll
            for (int j = 0; j < 4; ++j)
                acc[i][j] = __builtin_amdgcn_mfma_f32_16x16x32_bf16(af[i], bfr[j], acc[i][j], 0, 0, 0);

        __syncthreads();
    }

    // --- Epilogue: bias + positional gather + store ---
    const float* pt0 = ptab;
    const float* pt1 = ptab + (size_t)V_DIM * D_DIM;
    const int rq = (lane >> 4) * 4;      // C/D row quad

    float bvals[4];
    #pragma unroll
    for (int j = 0; j < 4; ++j)
        bvals[j] = bias[n0 + wc + j * 16 + lr];

    #pragma unroll
    for (int i = 0; i < 4; ++i) {
        #pragma unroll
        for (int r = 0; r < 4; ++r) {
            int m = m0 + wr + i * 16 + rq + r;
            int c0 = coord[2 * m];
            int c1 = coord[2 * m + 1];
            if (c0 < 0) c0 = 0;
            if (c1 < 0) c1 = 0;
            int vld = valid[m];
            #pragma unroll
            for (int j = 0; j < 4; ++j) {
                int d = n0 + wc + j * 16 + lr;
                float v = acc[i][j][r] + bvals[j];
                if (vld)
                    v += pt0[(size_t)c1 * D_DIM + d] + pt1[(size_t)c0 * D_DIM + d];
                out[(size_t)m * D_DIM + d] = v;
            }
        }
    }
}

extern "C" void kernel_launch(void* const* d_in, const int* in_sizes, int n_in,
                              void* d_out, int out_size, void* d_ws, size_t ws_size,
                              hipStream_t stream) {
    const float* x     = (const float*)d_in[0];
    const int*   coord = (const int*)d_in[1];
    const int*   valid = (const int*)d_in[2];
    const float* W     = (const float*)d_in[3];
    const float* ptab  = (const float*)d_in[4];

    float* out0 = (float*)d_out;                       // [32768][768]
    float* out1 = out0 + (size_t)ROWS * D_DIM;         // [32768][2]
    float* out2 = out1 + (size_t)ROWS * 2;             // [32768]

    __bf16* Wp  = (__bf16*)d_ws;                               // 768*768 bf16
    float*  bias = (float*)((char*)d_ws + (size_t)D_DIM * D_DIM * sizeof(__bf16));

    hipLaunchKernelGGL(prep_w, dim3(D_DIM), dim3(256), 0, stream, W, Wp, bias);
    hipLaunchKernelGGL(aux_out, dim3(ROWS / 256), dim3(256), 0, stream, coord, valid, out1, out2);
    hipLaunchKernelGGL(gemm_pos, dim3(D_DIM / BN, ROWS / BM), dim3(256), 0, stream,
                       x, Wp, bias, ptab, coord, valid, out0);
}

// Round 3
// 286.384 us; speedup vs baseline: 1.0623x; 1.0583x over previous
//
#include <hip/hip_runtime.h>
#include <hip/hip_bf16.h>
#include <cstddef>

#define D_DIM 768
#define V_DIM 10240
#define ROWS 32768   // B*N = 8*4096
#define BM 128
#define BN 128
#define BK 32

using bf16x8 = __attribute__((ext_vector_type(8))) __bf16;
using f32x4  = __attribute__((ext_vector_type(4))) float;

// ---------------------------------------------------------------------------
// Pre-pass: fold permutation + 2*(x-0.5) affine into weights.
// W'[d][j] = 2 * W[d][perm(j)],  perm(j) = (j%3)*256 + (j/48)*16 + (j/3)%16
// bias[d]  = -sum_k W[d][k]
// ---------------------------------------------------------------------------
__global__ void prep_w(const float* __restrict__ W, __bf16* __restrict__ Wp,
                       float* __restrict__ bias) {
    int d = blockIdx.x;
    int t = threadIdx.x;
    float s = 0.f;
    for (int j = t; j < D_DIM; j += 256) {
        int c  = j % 3;
        int pw = (j / 3) & 15;
        int ph = j / 48;
        int k  = c * 256 + ph * 16 + pw;
        float w = W[d * D_DIM + k];
        Wp[d * D_DIM + j] = (__bf16)(2.0f * w);
        s += w;
    }
    __shared__ float red[256];
    red[t] = s;
    __syncthreads();
    for (int off = 128; off > 0; off >>= 1) {
        if (t < off) red[t] += red[t + off];
        __syncthreads();
    }
    if (t == 0) bias[d] = -red[0];
}

// ---------------------------------------------------------------------------
// Streaming prepass: x fp32 -> bf16 (8 elems/thread), fused aux outputs.
// ---------------------------------------------------------------------------
__global__ void conv_aux(const float* __restrict__ X, __bf16* __restrict__ Xb,
                         const int* __restrict__ coord, const int* __restrict__ valid,
                         float* __restrict__ out1, float* __restrict__ out2) {
    int i = blockIdx.x * blockDim.x + threadIdx.x;
    size_t base = (size_t)i * 8;
    const float4* src = (const float4*)(X + base);
    float4 f0 = src[0];
    float4 f1 = src[1];
    bf16x8 v;
    v[0] = (__bf16)f0.x; v[1] = (__bf16)f0.y; v[2] = (__bf16)f0.z; v[3] = (__bf16)f0.w;
    v[4] = (__bf16)f1.x; v[5] = (__bf16)f1.y; v[6] = (__bf16)f1.z; v[7] = (__bf16)f1.w;
    *(bf16x8*)(Xb + base) = v;

    if (i < ROWS) {
        int c0 = coord[2 * i];
        int c1 = coord[2 * i + 1];
        out1[2 * i]     = (float)c1;
        out1[2 * i + 1] = (float)c0;
        out2[i] = valid[i] ? 0.0f : 1.0f;
    }
}

// ---------------------------------------------------------------------------
// Aux-only kernel (fallback path when ws can't hold bf16 X).
// ---------------------------------------------------------------------------
__global__ void aux_out(const int* __restrict__ coord, const int* __restrict__ valid,
                        float* __restrict__ out1, float* __restrict__ out2) {
    int i = blockIdx.x * blockDim.x + threadIdx.x;
    if (i < ROWS) {
        int c0 = coord[2 * i];
        int c1 = coord[2 * i + 1];
        out1[2 * i]     = (float)c1;
        out1[2 * i + 1] = (float)c0;
        out2[i] = valid[i] ? 0.0f : 1.0f;
    }
}

// ---------------------------------------------------------------------------
// Fast GEMM: both A (bf16 X) and B (Wp) staged via global_load_lds width=16.
// out[m][d] = sum_k Xb[m][k]*Wp[d][k] + bias[d] + pos[m][d]
// 128x128 tile, BK=32, 4 waves (2x2 of 64x64), 16x16x32 bf16 MFMA, 4x4 acc.
// ---------------------------------------------------------------------------
__launch_bounds__(256)
__global__ void gemm_fast(const __bf16* __restrict__ Xb, const __bf16* __restrict__ Wp,
                          const float* __restrict__ bias, const float* __restrict__ ptab,
                          const int* __restrict__ coord, const int* __restrict__ valid,
                          float* __restrict__ out) {
    __shared__ __align__(16) __bf16 la[BM * BK];
    __shared__ __align__(16) __bf16 lb[BN * BK];

    const int n0 = blockIdx.x * BN;
    const int m0 = blockIdx.y * BM;

    const int tid  = threadIdx.x;
    const int lane = tid & 63;
    const int wave = tid >> 6;
    const int wr   = (wave >> 1) * 64;
    const int wc   = (wave & 1) * 64;
    const int lr   = lane & 15;
    const int kq   = (lane >> 4) * 8;

    f32x4 acc[4][4] = {};

    for (int kt = 0; kt < D_DIM / BK; ++kt) {
        const int k0 = kt * BK;

        #pragma unroll
        for (int i = 0; i < 2; ++i) {
            int idx = i * 2048 + tid * 8;   // bf16 elem index within tile
            int row = idx >> 5;
            int col = idx & 31;
            const __bf16* srcA = Xb + (size_t)(m0 + row) * D_DIM + k0 + col;
            __builtin_amdgcn_global_load_lds(
                (const __attribute__((address_space(1))) void*)srcA,
                (__attribute__((address_space(3))) void*)&la[idx], 16, 0, 0);
            const __bf16* srcB = Wp + (size_t)(n0 + row) * D_DIM + k0 + col;
            __builtin_amdgcn_global_load_lds(
                (const __attribute__((address_space(1))) void*)srcB,
                (__attribute__((address_space(3))) void*)&lb[idx], 16, 0, 0);
        }

        __syncthreads();

        bf16x8 af[4], bfr[4];
        #pragma unroll
        for (int i = 0; i < 4; ++i)
            af[i] = *(const bf16x8*)&la[(wr + i * 16 + lr) * BK + kq];
        #pragma unroll
        for (int j = 0; j < 4; ++j)
            bfr[j] = *(const bf16x8*)&lb[(wc + j * 16 + lr) * BK + kq];

        #pragma unroll
        for (int i = 0; i < 4; ++i)
            #pragma unroll
            for (int j = 0; j < 4; ++j)
                acc[i][j] = __builtin_amdgcn_mfma_f32_16x16x32_bf16(af[i], bfr[j], acc[i][j], 0, 0, 0);

        __syncthreads();
    }

    const float* pt0 = ptab;
    const float* pt1 = ptab + (size_t)V_DIM * D_DIM;
    const int rq = (lane >> 4) * 4;

    float bvals[4];
    #pragma unroll
    for (int j = 0; j < 4; ++j)
        bvals[j] = bias[n0 + wc + j * 16 + lr];

    #pragma unroll
    for (int i = 0; i < 4; ++i) {
        #pragma unroll
        for (int r = 0; r < 4; ++r) {
            int m = m0 + wr + i * 16 + rq + r;
            int c0 = coord[2 * m];
            int c1 = coord[2 * m + 1];
            if (c0 < 0) c0 = 0;
            if (c1 < 0) c1 = 0;
            int vld = valid[m];
            #pragma unroll
            for (int j = 0; j < 4; ++j) {
                int d = n0 + wc + j * 16 + lr;
                float v = acc[i][j][r] + bvals[j];
                if (vld)
                    v += pt0[(size_t)c1 * D_DIM + d] + pt1[(size_t)c0 * D_DIM + d];
                out[(size_t)m * D_DIM + d] = v;
            }
        }
    }
}

// ---------------------------------------------------------------------------
// Fallback GEMM (fp32 X staged through registers) — round-1 structure.
// ---------------------------------------------------------------------------
__launch_bounds__(256)
__global__ void gemm_slow(const float* __restrict__ X, const __bf16* __restrict__ Wp,
                          const float* __restrict__ bias, const float* __restrict__ ptab,
                          const int* __restrict__ coord, const int* __restrict__ valid,
                          float* __restrict__ out) {
    __shared__ __align__(16) __bf16 la[BM * BK];
    __shared__ __align__(16) __bf16 lb[BN * BK];

    const int n0 = blockIdx.x * BN;
    const int m0 = blockIdx.y * BM;

    const int tid  = threadIdx.x;
    const int lane = tid & 63;
    const int wave = tid >> 6;
    const int wr   = (wave >> 1) * 64;
    const int wc   = (wave & 1) * 64;
    const int lr   = lane & 15;
    const int kq   = (lane >> 4) * 8;

    f32x4 acc[4][4] = {};

    for (int kt = 0; kt < D_DIM / BK; ++kt) {
        const int k0 = kt * BK;

        #pragma unroll
        for (int i = 0; i < 2; ++i) {
            int idx = i * 2048 + tid * 8;
            int row = idx >> 5;
            int col = idx & 31;
            const __bf16* src = Wp + (size_t)(n0 + row) * D_DIM + k0 + col;
            __builtin_amdgcn_global_load_lds(
                (const __attribute__((address_space(1))) void*)src,
                (__attribute__((address_space(3))) void*)&lb[idx], 16, 0, 0);
        }

        #pragma unroll
        for (int i = 0; i < 2; ++i) {
            int idx = i * 2048 + tid * 8;
            int row = idx >> 5;
            int col = idx & 31;
            const float4* src = (const float4*)(X + (size_t)(m0 + row) * D_DIM + k0 + col);
            float4 f0 = src[0];
            float4 f1 = src[1];
            bf16x8 v;
            v[0] = (__bf16)f0.x; v[1] = (__bf16)f0.y; v[2] = (__bf16)f0.z; v[3] = (__bf16)f0.w;
            v[4] = (__bf16)f1.x; v[5] = (__bf16)f1.y; v[6] = (__bf16)f1.z; v[7] = (__bf16)f1.w;
            *(bf16x8*)&la[idx] = v;
        }

        __syncthreads();

        bf16x8 af[4], bfr[4];
        #pragma unroll
        for (int i = 0; i < 4; ++i)
            af[i] = *(const bf16x8*)&la[(wr + i * 16 + lr) * BK + kq];
        #pragma unroll
        for (int j = 0; j < 4; ++j)
            bfr[j] = *(const bf16x8*)&lb[(wc + j * 16 + lr) * BK + kq];

        #pragma unroll
        for (int i = 0; i < 4; ++i)
            #pragma unroll
            for (int j = 0; j < 4; ++j)
                acc[i][j] = __builtin_amdgcn_mfma_f32_16x16x32_bf16(af[i], bfr[j], acc[i][j], 0, 0, 0);

        __syncthreads();
    }

    const float* pt0 = ptab;
    const float* pt1 = ptab + (size_t)V_DIM * D_DIM;
    const int rq = (lane >> 4) * 4;

    float bvals[4];
    #pragma unroll
    for (int j = 0; j < 4; ++j)
        bvals[j] = bias[n0 + wc + j * 16 + lr];

    #pragma unroll
    for (int i = 0; i < 4; ++i) {
        #pragma unroll
        for (int r = 0; r < 4; ++r) {
            int m = m0 + wr + i * 16 + rq + r;
            int c0 = coord[2 * m];
            int c1 = coord[2 * m + 1];
            if (c0 < 0) c0 = 0;
            if (c1 < 0) c1 = 0;
            int vld = valid[m];
            #pragma unroll
            for (int j = 0; j < 4; ++j) {
                int d = n0 + wc + j * 16 + lr;
                float v = acc[i][j][r] + bvals[j];
                if (vld)
                    v += pt0[(size_t)c1 * D_DIM + d] + pt1[(size_t)c0 * D_DIM + d];
                out[(size_t)m * D_DIM + d] = v;
            }
        }
    }
}

extern "C" void kernel_launch(void* const* d_in, const int* in_sizes, int n_in,
                              void* d_out, int out_size, void* d_ws, size_t ws_size,
                              hipStream_t stream) {
    const float* x     = (const float*)d_in[0];
    const int*   coord = (const int*)d_in[1];
    const int*   valid = (const int*)d_in[2];
    const float* W     = (const float*)d_in[3];
    const float* ptab  = (const float*)d_in[4];

    float* out0 = (float*)d_out;                       // [32768][768]
    float* out1 = out0 + (size_t)ROWS * D_DIM;         // [32768][2]
    float* out2 = out1 + (size_t)ROWS * 2;             // [32768]

    // Workspace layout: [Xb bf16 48MB][Wp bf16 1.125MB][bias 3KB]
    const size_t xb_bytes = (size_t)ROWS * D_DIM * sizeof(__bf16);   // 50,331,648
    const size_t wp_bytes = (size_t)D_DIM * D_DIM * sizeof(__bf16);  //  1,179,648
    const size_t need = xb_bytes + wp_bytes + D_DIM * sizeof(float);

    if (ws_size >= need) {
        __bf16* Xb  = (__bf16*)d_ws;
        __bf16* Wp  = (__bf16*)((char*)d_ws + xb_bytes);
        float* bias = (float*)((char*)d_ws + xb_bytes + wp_bytes);

        hipLaunchKernelGGL(prep_w, dim3(D_DIM), dim3(256), 0, stream, W, Wp, bias);
        hipLaunchKernelGGL(conv_aux, dim3((ROWS * D_DIM / 8) / 256), dim3(256), 0, stream,
                           x, Xb, coord, valid, out1, out2);
        hipLaunchKernelGGL(gemm_fast, dim3(D_DIM / BN, ROWS / BM), dim3(256), 0, stream,
                           Xb, Wp, bias, ptab, coord, valid, out0);
    } else {
        __bf16* Wp  = (__bf16*)d_ws;
        float* bias = (float*)((char*)d_ws + wp_bytes);

        hipLaunchKernelGGL(prep_w, dim3(D_DIM), dim3(256), 0, stream, W, Wp, bias);
        hipLaunchKernelGGL(aux_out, dim3(ROWS / 256), dim3(256), 0, stream, coord, valid, out1, out2);
        hipLaunchKernelGGL(gemm_slow, dim3(D_DIM / BN, ROWS / BM), dim3(256), 0, stream,
                           x, Wp, bias, ptab, coord, valid, out0);
    }
}